// Round 5
// baseline (404.761 us; speedup 1.0000x reference)
//
#include <hip/hip_runtime.h>
#include <stdint.h>

// ---------------------------------------------------------------------------
// GCN block: 3 x [ h = leaky_relu(in @ W);  out = (adj + I) @ h ]
// B=64, N=4096, D=16.  GEMM M=4096 x C=1024 x K=4096 bf16 MFMA, fp32 accum.
// Round 5: r4 analysis -> gemm was LDS-port-bound (42 B/cyc reads + 21 B/cyc
// DMA writes vs 85 B/cyc b128 ceiling).  New gemm_bd: B operand loads
// global->VGPR directly (prefetch distance 1, drained by the barrier), only A
// goes through LDS (double-buffered, ONE barrier/iter).  LDS traffic/iter
// halves: 96 KB -> 48 KB.  Helper fix: linear_pack_t2 (256 serial blocks) ->
// fuse_linear_t (1024 blocks, 64x64 tile, LDS transpose, coalesced).
// Workspace: adjb 32MB | hb 8MB | p0 8MB | p1 8MB = 56MB
// ---------------------------------------------------------------------------

typedef __bf16 bf16x8 __attribute__((ext_vector_type(8)));
typedef float  f32x4  __attribute__((ext_vector_type(4)));
typedef unsigned short ushort8 __attribute__((ext_vector_type(8)));

typedef __attribute__((address_space(1))) void* as1p;
typedef __attribute__((address_space(3))) void* as3p;
#define GLOAD_LDS16(G, L) \
  __builtin_amdgcn_global_load_lds((as1p)(G), (as3p)(L), 16, 0, 0)

#define P_ELEMS 4194304  // elems per partial buffer (4096*1024)

__device__ __forceinline__ unsigned short f2bf(float f) {
  unsigned u = __float_as_uint(f);
  u += 0x7fffu + ((u >> 16) & 1u);  // RNE
  return (unsigned short)(u >> 16);
}
__device__ __forceinline__ float bf2f(unsigned short u) {
  return __uint_as_float(((unsigned)u) << 16);
}

// ---------------------------------------------------------------------------
// adjI = bf16(adj + I), 4096x4096.  1 thread = 16 contiguous elements.
// ---------------------------------------------------------------------------
__global__ void make_adjI(const float* __restrict__ adj,
                          unsigned short* __restrict__ adjb) {
  size_t t = (size_t)blockIdx.x * 256 + threadIdx.x;
  size_t base = t * 16;
  int n  = (int)(base >> 12);
  int m0 = (int)(base & 4095);
  const float4* src = (const float4*)(adj + base);
  float4 q0 = src[0], q1 = src[1], q2 = src[2], q3 = src[3];
  float vals[16] = {q0.x,q0.y,q0.z,q0.w, q1.x,q1.y,q1.z,q1.w,
                    q2.x,q2.y,q2.z,q2.w, q3.x,q3.y,q3.z,q3.w};
  ushort8 o0, o1;
#pragma unroll
  for (int j = 0; j < 8; j++) {
    float f = vals[j];     if (m0 + j == n)     f += 1.0f;
    o0[j] = f2bf(f);
  }
#pragma unroll
  for (int j = 0; j < 8; j++) {
    float f = vals[8 + j]; if (m0 + 8 + j == n) f += 1.0f;
    o1[j] = f2bf(f);
  }
  ushort8* dst = (ushort8*)(adjb + base);
  dst[0] = o0; dst[1] = o1;
}

// ---------------------------------------------------------------------------
// layer 0 linear: h = leaky_relu(x @ W), x (b,n,d) fp32 -> hT bf16 [c][n].
// ---------------------------------------------------------------------------
__global__ void linear_pack(const float* __restrict__ in,
                            const float* __restrict__ W,
                            unsigned short* __restrict__ hb) {
  int tid  = threadIdx.x;
  int lane = tid & 63;
  int bq   = tid >> 6;
  int n = blockIdx.x * 64 + lane;
  int b = blockIdx.y * 4 + bq;
  size_t off = ((size_t)b * 4096 + n) * 16;
  const float4* src = (const float4*)(in + off);
  float4 q0 = src[0], q1 = src[1], q2 = src[2], q3 = src[3];
  float xr[16] = {q0.x,q0.y,q0.z,q0.w, q1.x,q1.y,q1.z,q1.w,
                  q2.x,q2.y,q2.z,q2.w, q3.x,q3.y,q3.z,q3.w};
#pragma unroll
  for (int e = 0; e < 16; e++) {
    float acc = 0.f;
#pragma unroll
    for (int d = 0; d < 16; d++) acc += xr[d] * W[d * 16 + e];
    acc = acc > 0.f ? acc : 0.2f * acc;
    hb[(size_t)(b * 16 + e) * 4096 + n] = f2bf(acc);
  }
}

// ---------------------------------------------------------------------------
// layers 1,2: x = p0+p1 ([n][c] bf16); h = leaky_relu(x @ W); hT bf16 [c][n].
// 64n x 64c tile per block, grid (64,16) = 1024 blocks.  Coalesced loads,
// LDS transpose for coalesced stores.  xs stride 65 (2-way max, free);
// ht ushort rows: 64 lanes x 2B consecutive = 2-way (free).
// ---------------------------------------------------------------------------
__global__ void fuse_linear_t(const unsigned short* __restrict__ p,
                              const float* __restrict__ W,
                              unsigned short* __restrict__ hb) {
  __shared__ float xs[64 * 65];
  __shared__ unsigned short ht[64 * 72];
  int n0 = blockIdx.x * 64, c0 = blockIdx.y * 64;
  // load + add partials: 64 rows x 8 ushort8 chunks
  for (int idx = threadIdx.x; idx < 512; idx += 256) {
    int row = idx >> 3, ch = idx & 7;
    size_t g = (size_t)(n0 + row) * 1024 + c0 + ch * 8;
    ushort8 a = *(const ushort8*)(p + g);
    ushort8 b = *(const ushort8*)(p + P_ELEMS + g);
    float* dst = xs + row * 65 + ch * 8;
#pragma unroll
    for (int j = 0; j < 8; ++j) dst[j] = bf2f(a[j]) + bf2f(b[j]);
  }
  __syncthreads();
  // compute: thread = (n_l, b_l); W uniform -> scalar loads
  int n_l = threadIdx.x & 63, b_l = threadIdx.x >> 6;   // b_l 0..3
  const float* xr = xs + n_l * 65 + b_l * 16;
  float xv[16];
#pragma unroll
  for (int d = 0; d < 16; ++d) xv[d] = xr[d];
  float acc[16];
#pragma unroll
  for (int e = 0; e < 16; ++e) acc[e] = 0.f;
#pragma unroll
  for (int d = 0; d < 16; ++d)
#pragma unroll
    for (int e = 0; e < 16; ++e) acc[e] += xv[d] * W[d * 16 + e];
#pragma unroll
  for (int e = 0; e < 16; ++e) {
    float a = acc[e] > 0.f ? acc[e] : 0.2f * acc[e];
    ht[(b_l * 16 + e) * 72 + n_l] = f2bf(a);
  }
  __syncthreads();
  // store transposed: 64 c-rows x 8 ushort8 chunks, coalesced 16B
  for (int idx = threadIdx.x; idx < 512; idx += 256) {
    int row = idx >> 3, ch = idx & 7;
    ushort8 v = *(const ushort8*)(ht + row * 72 + ch * 8);
    *(ushort8*)(hb + (size_t)(c0 + row) * 4096 + n0 + ch * 8) = v;
  }
}

// ---------------------------------------------------------------------------
// final: out fp32 (b,n,d) = p0 + p1 (both already in (b,n,d) bf16 layout)
// ---------------------------------------------------------------------------
__global__ void add_out(const unsigned short* __restrict__ p,
                        float* __restrict__ out) {
  int i8 = (blockIdx.x * 256 + threadIdx.x) * 8;
  ushort8 a = *(const ushort8*)(p + i8);
  ushort8 b = *(const ushort8*)(p + P_ELEMS + i8);
  float4 o0, o1;
  o0.x = bf2f(a[0]) + bf2f(b[0]);  o0.y = bf2f(a[1]) + bf2f(b[1]);
  o0.z = bf2f(a[2]) + bf2f(b[2]);  o0.w = bf2f(a[3]) + bf2f(b[3]);
  o1.x = bf2f(a[4]) + bf2f(b[4]);  o1.y = bf2f(a[5]) + bf2f(b[5]);
  o1.z = bf2f(a[6]) + bf2f(b[6]);  o1.w = bf2f(a[7]) + bf2f(b[7]);
  *(float4*)(out + i8)     = o0;
  *(float4*)(out + i8 + 4) = o1;
}

// ---------------------------------------------------------------------------
// partial[n][c] (ks half) = adjI[n0..][k] * hT[c0..][k].
// B operand: global->VGPR, prefetch distance 1 (barrier drain = ready point).
// A operand: global_load_lds into double buffer, ONE barrier per iter.
// grid 512 = 32mt x 8ct x 2ks, xcd = mt&7.  Tile 128x128, BK=64, 4 waves 2x2.
// A XOR swizzle: phys 16B chunk = logical ^ (row&7)  [0 conflicts, verified]
// ---------------------------------------------------------------------------
__global__ __launch_bounds__(256, 2)
void gemm_bd(const unsigned short* __restrict__ A,
             const unsigned short* __restrict__ Bm,
             unsigned short* __restrict__ outp, int final_mode) {
  const int K = 4096;
  __shared__ __bf16 a_s[2][128 * 64];   // 2 x 16 KB

  int tid = threadIdx.x, wave = tid >> 6, lane = tid & 63;

  int lin = blockIdx.x;
  int xcd = lin & 7, g = lin >> 3;
  int mth = g & 3, ct = (g >> 2) & 7, ks = g >> 5;   // ks in {0,1}
  int mt = mth * 8 + xcd;
  int n0 = mt * 128, c0 = ct * 128;
  int kbase = ks * 2048;

  // A staging addressing (XOR swizzle on global side)
  int l8 = lane >> 3, lc = lane & 7;
  int swc = lc ^ l8;
  const unsigned short* gA[4];
#pragma unroll
  for (int j = 0; j < 4; ++j) {
    int r = wave * 32 + j * 8 + l8;
    gA[j] = A + (size_t)(n0 + r) * K + kbase + swc * 8;
  }

  int i16 = lane & 15, q = lane >> 4;
  int wm = wave >> 1, wn = wave & 1;
  int sw7 = i16 & 7;

  // B fragment base pointers: row = c0 + wn*64 + u*16 + i16, col = kbase + q*8
  const unsigned short* gBu[4];
#pragma unroll
  for (int u = 0; u < 4; ++u)
    gBu[u] = Bm + (size_t)(c0 + wn * 64 + u * 16 + i16) * K + kbase + q * 8;

  f32x4 acc[4][4] = {};
  bf16x8 bcur[2][4], bnext[2][4];

  // prologue: DMA A(0) -> buf0; load B(0) -> regs
#pragma unroll
  for (int j = 0; j < 4; ++j)
    GLOAD_LDS16(gA[j], &a_s[0][(wave * 32 + j * 8) * 64]);
#pragma unroll
  for (int s = 0; s < 2; ++s)
#pragma unroll
    for (int u = 0; u < 4; ++u)
      bcur[s][u] = *(const bf16x8*)(gBu[u] + s * 32);

#pragma unroll 2
  for (int it = 0; it < 32; ++it) {
    // barrier: (a) all waves done reading buf[(it+1)&1] from iter it-1,
    // (b) vmcnt(0) drain completes A(it) DMA and B(it) register loads.
    __syncthreads();
    if (it + 1 < 32) {
#pragma unroll
      for (int j = 0; j < 4; ++j)
        GLOAD_LDS16(gA[j] + (it + 1) * 64,
                    &a_s[(it + 1) & 1][(wave * 32 + j * 8) * 64]);
    }
    int itn = (it + 1 < 32) ? it + 1 : 0;   // clamped prefetch (last redundant)
#pragma unroll
    for (int s = 0; s < 2; ++s)
#pragma unroll
      for (int u = 0; u < 4; ++u)
        bnext[s][u] = *(const bf16x8*)(gBu[u] + itn * 64 + s * 32);

    const __bf16* ab = a_s[it & 1];
#pragma unroll
    for (int s = 0; s < 2; ++s) {
      int pc = (s * 4 + q) ^ sw7;
#pragma unroll
      for (int t = 0; t < 4; ++t) {
        bf16x8 af = *(const bf16x8*)(ab + (wm * 64 + t * 16 + i16) * 64 + pc * 8);
#pragma unroll
        for (int u = 0; u < 4; ++u)
          acc[t][u] = __builtin_amdgcn_mfma_f32_16x16x32_bf16(af, bcur[s][u], acc[t][u], 0, 0, 0);
      }
    }
#pragma unroll
    for (int s = 0; s < 2; ++s)
#pragma unroll
      for (int u = 0; u < 4; ++u)
        bcur[s][u] = bnext[s][u];
  }

  // epilogue: plain bf16 stores of this K-half's partial into p[ks]
  unsigned short* dst = outp + (size_t)ks * P_ELEMS;
#pragma unroll
  for (int t = 0; t < 4; ++t)
#pragma unroll
    for (int u = 0; u < 4; ++u)
#pragma unroll
      for (int i = 0; i < 4; ++i) {
        int n_g = n0 + wm * 64 + t * 16 + q * 4 + i;
        int c_g = c0 + wn * 64 + u * 16 + i16;
        size_t off = final_mode
            ? ((size_t)(c_g >> 4) * 65536 + (size_t)n_g * 16 + (c_g & 15))
            : ((size_t)n_g * 1024 + c_g);
        dst[off] = f2bf(acc[t][u][i]);
      }
}

// ---------------------------------------------------------------------------
extern "C" void kernel_launch(void* const* d_in, const int* in_sizes, int n_in,
                              void* d_out, int out_size, void* d_ws, size_t ws_size,
                              hipStream_t stream) {
  const float* x   = (const float*)d_in[0];
  const float* adj = (const float*)d_in[1];
  // d_in[2] = Identity (folded analytically)
  const float* W0  = (const float*)d_in[3];
  const float* W1  = (const float*)d_in[4];
  const float* W2  = (const float*)d_in[5];
  float* out = (float*)d_out;

  char* ws = (char*)d_ws;
  unsigned short* adjb = (unsigned short*)ws;                 // 32 MiB
  unsigned short* hb   = (unsigned short*)(ws + 33554432);    //  8 MiB
  unsigned short* pp   = (unsigned short*)(ws + 41943040);    // p0|p1, 16 MiB

  make_adjI<<<4096, 256, 0, stream>>>(adj, adjb);

  // layer 0
  linear_pack<<<dim3(64, 16), 256, 0, stream>>>(x, W0, hb);
  gemm_bd<<<512, 256, 0, stream>>>(adjb, hb, pp, 0);
  // layer 1
  fuse_linear_t<<<dim3(64, 16), 256, 0, stream>>>(pp, W1, hb);
  gemm_bd<<<512, 256, 0, stream>>>(adjb, hb, pp, 0);
  // layer 2
  fuse_linear_t<<<dim3(64, 16), 256, 0, stream>>>(pp, W2, hb);
  gemm_bd<<<512, 256, 0, stream>>>(adjb, hb, pp, 1);
  add_out<<<2048, 256, 0, stream>>>(pp, out);
}

// Round 6
// 261.851 us; speedup vs baseline: 1.5458x; 1.5458x over previous
//
#include <hip/hip_runtime.h>
#include <stdint.h>

// ---------------------------------------------------------------------------
// GCN block: 3 x [ h = leaky_relu(in @ W);  out = adj@h + h ]   (I folded OUT)
// B=64, N=4096, D=16.  GEMM M=4096 x C=1024 x K=4096 in FP8 e4m3 MFMA,
// fp32 accum.  Round 6: r4 was LDS-port-bound (96 KB/block-iter at 128 B/cyc
// = measured 1551 cyc).  fp8 + BK=128 keeps the identical staging geometry
// (XOR swizzle, 8 DMA/wave/iter, 2 blocks/CU) but doubles MACs per LDS byte.
// adj scaled x4096 into e4m3 (descale in epilogue); identity term uses a
// bf16 h copy (h_nc) added in consumers, so fp8 error only rides tiny adj.
// ws: adj8 16MB | hb8 4MB | h_nc 8MB | p0 8MB | p1 8MB = 44MB
// ---------------------------------------------------------------------------

typedef float  f32x4  __attribute__((ext_vector_type(4)));
typedef unsigned short ushort8 __attribute__((ext_vector_type(8)));
typedef long   i64x2  __attribute__((ext_vector_type(2)));

typedef __attribute__((address_space(1))) void* as1p;
typedef __attribute__((address_space(3))) void* as3p;
#define GLOAD_LDS16(G, L) \
  __builtin_amdgcn_global_load_lds((as1p)(G), (as3p)(L), 16, 0, 0)

#define P_ELEMS 4194304       // elems per partial buffer (4096*1024)
#define ADJ_SCALE 4096.0f
#define ADJ_DESCALE (1.0f / 4096.0f)

__device__ __forceinline__ unsigned short f2bf(float f) {
  unsigned u = __float_as_uint(f);
  u += 0x7fffu + ((u >> 16) & 1u);  // RNE
  return (unsigned short)(u >> 16);
}
__device__ __forceinline__ float bf2f(unsigned short u) {
  return __uint_as_float(((unsigned)u) << 16);
}
// pack 4 fp32 -> 4 fp8 e4m3 bytes (RNE, saturating)
__device__ __forceinline__ int pk4_fp8(float a, float b, float c, float d) {
  int v = __builtin_amdgcn_cvt_pk_fp8_f32(a, b, 0, false);   // bytes 0,1
  v = __builtin_amdgcn_cvt_pk_fp8_f32(c, d, v, true);        // bytes 2,3
  return v;
}

// ---------------------------------------------------------------------------
// adj8 = e4m3(adj * 4096), 4096x4096.  1 thread = 16 contiguous elements.
// ---------------------------------------------------------------------------
__global__ void make_adj8(const float* __restrict__ adj,
                          unsigned char* __restrict__ a8) {
  size_t base = ((size_t)blockIdx.x * 256 + threadIdx.x) * 16;
  const float4* src = (const float4*)(adj + base);
  float4 q0 = src[0], q1 = src[1], q2 = src[2], q3 = src[3];
  int4 o;
  o.x = pk4_fp8(q0.x * ADJ_SCALE, q0.y * ADJ_SCALE, q0.z * ADJ_SCALE, q0.w * ADJ_SCALE);
  o.y = pk4_fp8(q1.x * ADJ_SCALE, q1.y * ADJ_SCALE, q1.z * ADJ_SCALE, q1.w * ADJ_SCALE);
  o.z = pk4_fp8(q2.x * ADJ_SCALE, q2.y * ADJ_SCALE, q2.z * ADJ_SCALE, q2.w * ADJ_SCALE);
  o.w = pk4_fp8(q3.x * ADJ_SCALE, q3.y * ADJ_SCALE, q3.z * ADJ_SCALE, q3.w * ADJ_SCALE);
  *(int4*)(a8 + base) = o;
}

// ---------------------------------------------------------------------------
// linear layer, 64n x 64c tile per block, grid (64,16).
// mode 0: u = x (fp32 (b,n,d))           [layer 0]
// mode 1: u = p0 + p1 + h_nc (bf16)      [layers 1,2; also = prev layer out]
// h = leaky_relu(u @ W);  writes hb8 fp8 [c][n] (GEMM B operand, via LDS
// transpose) and h_nc bf16 [n][c] (identity term for consumers).
// ---------------------------------------------------------------------------
__global__ void linear_fuse(const float* __restrict__ x,
                            const unsigned short* __restrict__ pp,
                            const unsigned short* __restrict__ hnc_in,
                            const float* __restrict__ W,
                            unsigned char* __restrict__ hb8,
                            unsigned short* __restrict__ hnc_out,
                            int mode) {
  __shared__ float xs[64 * 65];
  __shared__ unsigned short ht[64 * 72];
  int n0 = blockIdx.x * 64, c0 = blockIdx.y * 64;

  if (mode == 0) {
    for (int i = threadIdx.x; i < 1024; i += 256) {
      int bs = i >> 8, rem = i & 255, nr = rem >> 2, d4 = rem & 3;
      float4 v = *(const float4*)(
          x + ((size_t)(c0 / 16 + bs) * 4096 + n0 + nr) * 16 + d4 * 4);
      float* dst = xs + nr * 65 + bs * 16 + d4 * 4;
      dst[0] = v.x; dst[1] = v.y; dst[2] = v.z; dst[3] = v.w;
    }
  } else {
    for (int i = threadIdx.x; i < 512; i += 256) {
      int row = i >> 3, ch = i & 7;
      size_t g = (size_t)(n0 + row) * 1024 + c0 + ch * 8;
      ushort8 a = *(const ushort8*)(pp + g);
      ushort8 b = *(const ushort8*)(pp + P_ELEMS + g);
      ushort8 c = *(const ushort8*)(hnc_in + g);
      float* dst = xs + row * 65 + ch * 8;
#pragma unroll
      for (int j = 0; j < 8; ++j) dst[j] = bf2f(a[j]) + bf2f(b[j]) + bf2f(c[j]);
    }
  }
  __syncthreads();

  int n_l = threadIdx.x & 63, b_l = threadIdx.x >> 6;   // b_l 0..3
  float xv[16];
#pragma unroll
  for (int d = 0; d < 16; ++d) xv[d] = xs[n_l * 65 + b_l * 16 + d];
  float accv[16];
#pragma unroll
  for (int e = 0; e < 16; ++e) accv[e] = 0.f;
#pragma unroll
  for (int d = 0; d < 16; ++d)
#pragma unroll
    for (int e = 0; e < 16; ++e) accv[e] += xv[d] * W[d * 16 + e];

  ushort8 h0, h1;
#pragma unroll
  for (int e = 0; e < 16; ++e) {
    float a = accv[e] > 0.f ? accv[e] : 0.2f * accv[e];
    unsigned short hv = f2bf(a);
    ht[(b_l * 16 + e) * 72 + n_l] = hv;
    if (e < 8) h0[e] = hv; else h1[e - 8] = hv;
  }
  unsigned short* ho = hnc_out + (size_t)(n0 + n_l) * 1024 + c0 + b_l * 16;
  *(ushort8*)(ho)     = h0;
  *(ushort8*)(ho + 8) = h1;
  __syncthreads();

  // fp8 transposed store: 64 c-rows x 8 chunks of 8 bf16 -> 8 fp8 bytes
  for (int i = threadIdx.x; i < 512; i += 256) {
    int row = i >> 3, ch = i & 7;
    const unsigned short* s = ht + row * 72 + ch * 8;
    int2 v;
    v.x = pk4_fp8(bf2f(s[0]), bf2f(s[1]), bf2f(s[2]), bf2f(s[3]));
    v.y = pk4_fp8(bf2f(s[4]), bf2f(s[5]), bf2f(s[6]), bf2f(s[7]));
    *(int2*)(hb8 + (size_t)(c0 + row) * 4096 + n0 + ch * 8) = v;
  }
}

// ---------------------------------------------------------------------------
// final: out fp32 (b,n,d) = p0 + p1 + h_nc   (all stored [n][c] bf16)
// ---------------------------------------------------------------------------
__global__ void add_out(const unsigned short* __restrict__ pp,
                        const unsigned short* __restrict__ hnc,
                        float* __restrict__ out) {
  int gid = blockIdx.x * 256 + threadIdx.x;      // 0..524287
  int n = gid >> 7, c8 = (gid & 127) * 8;
  size_t g = (size_t)n * 1024 + c8;
  ushort8 a = *(const ushort8*)(pp + g);
  ushort8 b = *(const ushort8*)(pp + P_ELEMS + g);
  ushort8 h = *(const ushort8*)(hnc + g);
  float v[8];
#pragma unroll
  for (int j = 0; j < 8; ++j) v[j] = bf2f(a[j]) + bf2f(b[j]) + bf2f(h[j]);
  int bb = c8 >> 4, d0 = c8 & 15;                // d0 = 0 or 8
  float* o = out + (size_t)bb * 65536 + n * 16 + d0;
  *(float4*)(o)     = float4{v[0], v[1], v[2], v[3]};
  *(float4*)(o + 4) = float4{v[4], v[5], v[6], v[7]};
}

// ---------------------------------------------------------------------------
// p[ks][n][c] = (adj8[n0..][k] * hb8[c0..][k]) / 4096   (one K-half per block)
// fp8 e4m3 MFMA 16x16x32, BK=128 (rows 128 B = 8 x 16B chunks).
// Geometry identical to r4: grid 512 = 32mt x 8ct x 2ks, xcd = mt&7,
// 4 waves 2x2, wave tile 64x64, XOR swizzle phys = logical ^ (row&7).
// Per block-iter: 96 KB LDS traffic for 2.1M MACs (2x r4's MAC/byte).
// MFMA contracts position-wise, so A/B just need identical k-major layout.
// ---------------------------------------------------------------------------
__global__ __launch_bounds__(256, 2)
void gemm_f8(const unsigned char* __restrict__ A,
             const unsigned char* __restrict__ B8,
             unsigned short* __restrict__ pp) {
  const int K = 4096;
  __shared__ unsigned char a_s[128 * 128];   // 16 KB
  __shared__ unsigned char b_s[128 * 128];   // 16 KB

  int tid = threadIdx.x, wave = tid >> 6, lane = tid & 63;

  int lin = blockIdx.x;
  int xcd = lin & 7, g = lin >> 3;
  int mth = g & 3, ct = (g >> 2) & 7, ks = g >> 5;   // ks in {0,1}
  int mt = mth * 8 + xcd;
  int n0 = mt * 128, c0 = ct * 128;
  int kbase = ks * 2048;

  // staging: wave w covers rows w*32..w*32+31 (4 insts each operand)
  int l8 = lane >> 3, lc = lane & 7;
  int swc = lc ^ l8;                 // logical chunk fetched into phys lc
  const unsigned char* gA[4];
  const unsigned char* gB[4];
#pragma unroll
  for (int j = 0; j < 4; ++j) {
    int r = wave * 32 + j * 8 + l8;
    gA[j] = A  + (size_t)(n0 + r) * K + kbase + swc * 16;
    gB[j] = B8 + (size_t)(c0 + r) * K + kbase + swc * 16;
  }

  int i16 = lane & 15, q = lane >> 4;
  int wm = wave >> 1, wn = wave & 1;
  int sw7 = i16 & 7;

  f32x4 acc[4][4] = {};

  for (int it = 0; it < 16; ++it) {
    int k0 = it * 128;
    __syncthreads();                 // prev reads done before overwrite
#pragma unroll
    for (int j = 0; j < 4; ++j) {
      GLOAD_LDS16(gA[j] + k0, a_s + (wave * 32 + j * 8) * 128);
      GLOAD_LDS16(gB[j] + k0, b_s + (wave * 32 + j * 8) * 128);
    }
    __syncthreads();                 // drains staging -> visible
#pragma unroll
    for (int s = 0; s < 2; ++s) {
      int pc = ((s * 4 + q) ^ sw7) * 16;
      i64x2 bv[4];
#pragma unroll
      for (int u = 0; u < 4; ++u)
        bv[u] = *(const i64x2*)(b_s + (wn * 64 + u * 16 + i16) * 128 + pc);
#pragma unroll
      for (int t = 0; t < 4; ++t) {
        i64x2 av = *(const i64x2*)(a_s + (wm * 64 + t * 16 + i16) * 128 + pc);
#pragma unroll
        for (int u = 0; u < 4; ++u) {
          acc[t][u] = __builtin_amdgcn_mfma_f32_16x16x32_fp8_fp8(av.x, bv[u].x, acc[t][u], 0, 0, 0);
          acc[t][u] = __builtin_amdgcn_mfma_f32_16x16x32_fp8_fp8(av.y, bv[u].y, acc[t][u], 0, 0, 0);
        }
      }
    }
  }

  // epilogue: descale + bf16 store of this K-half's partial
  unsigned short* dst = pp + (size_t)ks * P_ELEMS;
#pragma unroll
  for (int t = 0; t < 4; ++t)
#pragma unroll
    for (int u = 0; u < 4; ++u)
#pragma unroll
      for (int i = 0; i < 4; ++i) {
        int n_g = n0 + wm * 64 + t * 16 + q * 4 + i;
        int c_g = c0 + wn * 64 + u * 16 + i16;
        dst[(size_t)n_g * 1024 + c_g] = f2bf(acc[t][u][i] * ADJ_DESCALE);
      }
}

// ---------------------------------------------------------------------------
extern "C" void kernel_launch(void* const* d_in, const int* in_sizes, int n_in,
                              void* d_out, int out_size, void* d_ws, size_t ws_size,
                              hipStream_t stream) {
  const float* x   = (const float*)d_in[0];
  const float* adj = (const float*)d_in[1];
  // d_in[2] = Identity (handled as the +h_nc term)
  const float* W0  = (const float*)d_in[3];
  const float* W1  = (const float*)d_in[4];
  const float* W2  = (const float*)d_in[5];
  float* out = (float*)d_out;

  char* ws = (char*)d_ws;
  unsigned char*  adj8 = (unsigned char*)ws;                   // 16 MiB
  unsigned char*  hb8  = (unsigned char*)(ws + 16777216);      //  4 MiB
  unsigned short* hnc  = (unsigned short*)(ws + 20971520);     //  8 MiB
  unsigned short* pp   = (unsigned short*)(ws + 29360128);     // p0|p1 16 MiB

  make_adj8<<<4096, 256, 0, stream>>>(adj, adj8);

  // layer 0
  linear_fuse<<<dim3(64, 16), 256, 0, stream>>>(x, pp, hnc, W0, hb8, hnc, 0);
  gemm_f8<<<512, 256, 0, stream>>>(adj8, hb8, pp);
  // layer 1
  linear_fuse<<<dim3(64, 16), 256, 0, stream>>>(x, pp, hnc, W1, hb8, hnc, 1);
  gemm_f8<<<512, 256, 0, stream>>>(adj8, hb8, pp);
  // layer 2
  linear_fuse<<<dim3(64, 16), 256, 0, stream>>>(x, pp, hnc, W2, hb8, hnc, 1);
  gemm_f8<<<512, 256, 0, stream>>>(adj8, hb8, pp);
  add_out<<<2048, 256, 0, stream>>>(pp, hnc, out);
}